// Round 7
// baseline (540.994 us; speedup 1.0000x reference)
//
#include <hip/hip_runtime.h>

static constexpr int cT = 1024;   // tokens
static constexpr int cH = 1024;   // hidden
static constexpr int cI = 2816;   // intermediate
static constexpr int cE = 16;     // experts
static constexpr int cK = 4;      // top-k

typedef __attribute__((ext_vector_type(8))) short bf16x8;
typedef __attribute__((ext_vector_type(4))) float f32x4;
typedef __attribute__((ext_vector_type(2))) unsigned uint2v;
typedef __attribute__((ext_vector_type(4))) unsigned uint4v;

__device__ __forceinline__ unsigned f2bf(float f) {
  unsigned u = __float_as_uint(f);
  return (u + 0x7FFFu + ((u >> 16) & 1u)) >> 16;   // RNE f32->bf16
}
__device__ __forceinline__ unsigned pack2(float lo, float hi) {
  return f2bf(lo) | (f2bf(hi) << 16);
}

// Two ds_read_b64 (stride-34-uint layout is 8B- but not 16B-aligned).
__device__ __forceinline__ bf16x8 ld_bfrag(const unsigned* p) {
  union { uint2v d[2]; bf16x8 v; } r;
  r.d[0] = *(const uint2v*)p;
  r.d[1] = *(const uint2v*)(p + 2);
  return r.v;
}

// ------------------------------------------------------------- x -> bf16 ----
__global__ __launch_bounds__(256) void xcast_kernel(
    const float* __restrict__ x, unsigned short* __restrict__ xb) {
  const int i = blockIdx.x * 256 + threadIdx.x;
  const float4* xv = (const float4*)x;
  const float4 a = xv[i * 2], b = xv[i * 2 + 1];
  uint4v o;
  o.x = pack2(a.x, a.y); o.y = pack2(a.z, a.w);
  o.z = pack2(b.x, b.y); o.w = pack2(b.z, b.w);
  ((uint4v*)xb)[i] = o;
}

// ---------------------------------------------------------------- router ----
__global__ __launch_bounds__(64) void router_kernel(
    const float* __restrict__ x, const float* __restrict__ Wg,
    int* __restrict__ topk_id, float* __restrict__ topk_w,
    int* __restrict__ counts) {
  const int t = blockIdx.x;
  const int l = threadIdx.x;

  float xa[16];
#pragma unroll
  for (int i = 0; i < 16; ++i) xa[i] = x[(size_t)t * cH + l + 64 * i];

  float lg[16];
#pragma unroll
  for (int e = 0; e < 16; ++e) {
    float s = 0.f;
#pragma unroll
    for (int i = 0; i < 16; ++i) s += xa[i] * Wg[(size_t)e * cH + l + 64 * i];
#pragma unroll
    for (int d = 1; d < 64; d <<= 1) s += __shfl_xor(s, d);
    lg[e] = s;
  }

  if (l == 0) {
    int ids[4]; float vals[4];
    unsigned taken = 0;
#pragma unroll
    for (int j = 0; j < 4; ++j) {
      float m = -1e30f; int mi = 0;
#pragma unroll
      for (int e = 0; e < 16; ++e) {
        bool better = !((taken >> e) & 1u) && lg[e] > m;
        if (better) { m = lg[e]; mi = e; }
      }
      taken |= 1u << mi; ids[j] = mi; vals[j] = m;
    }
    const float mx = vals[0];
    float s = 0.f;
#pragma unroll
    for (int j = 0; j < 4; ++j) { vals[j] = __expf(vals[j] - mx); s += vals[j]; }
    const float inv = 1.f / s;
#pragma unroll
    for (int j = 0; j < 4; ++j) {
      topk_id[t * 4 + j] = ids[j];
      topk_w[t * 4 + j] = vals[j] * inv;
      atomicAdd(&counts[ids[j]], 1);
    }
  }
}

__global__ void scan_kernel(const int* __restrict__ counts,
                            int* __restrict__ offsets) {
  if (threadIdx.x == 0 && blockIdx.x == 0) {
    int acc = 0;
    for (int e = 0; e < cE; ++e) { offsets[e] = acc; acc += counts[e]; }
    offsets[cE] = acc;
  }
}

__global__ __launch_bounds__(256) void scatter_kernel(
    const int* __restrict__ topk_id, const int* __restrict__ offsets,
    int* __restrict__ cursor, int* __restrict__ pair_token,
    int* __restrict__ pair_pos) {
  const int i = blockIdx.x * 256 + threadIdx.x;   // 0..4095
  const int t = i >> 2;
  const int e = topk_id[i];
  const int pos = offsets[e] + atomicAdd(&cursor[e], 1);
  pair_token[pos] = t;
  pair_pos[i] = pos;
}

// ---------------------------------------------------------------- gate+up ---
// 512 threads = 8 waves: wave (mat = wid&1, msub = wid>>1) computes a 16-row
// m-slice of ONE matrix (gate or up). Per-thread state: 16 acc + 32 prefetch
// VGPRs -> depth-2 pipeline without spills. Stride-34 LDS layout (R3-proven).
// silu(g)*u combined via a one-time LDS exchange at the epilogue.
__global__ __launch_bounds__(512, 4) void gateup_kernel(
    const unsigned short* __restrict__ xb, const float* __restrict__ gw,
    const float* __restrict__ uw, const int* __restrict__ offsets,
    const int* __restrict__ pair_token, unsigned short* __restrict__ act) {
  const int e = blockIdx.y;
  const int off = offsets[e];
  const int n_e = offsets[e + 1] - off;
  const int strip = blockIdx.x >> 2;
  const int c0 = (blockIdx.x & 3) * 64;
  if (c0 >= n_e) return;
  const int nb = strip * 64;
  const int tid = threadIdx.x, l = tid & 63, wid = tid >> 6;
  const int q = l & 15, h16 = l >> 4;
  const int mat = wid & 1, msub = wid >> 1;

  __shared__ unsigned sB[2][2][2176];   // [buf][mat][col*34 + kpair]
  __shared__ int tokl[64];

  // staging: tm selects matrix; 256 threads per matrix, 4 rows x float4 each
  const int tm = tid >> 8, tt = tid & 255;
  const int rq = tt >> 4, cg = tt & 15;
  const float* wsrc = (tm ? uw : gw) + (size_t)e * cH * cI + nb + cg * 4;

  float4 s0[4], s1[4];

#define GU_LD(S, KT)                                                          \
  _Pragma("unroll")                                                           \
  for (int j = 0; j < 4; ++j)                                                 \
    S[j] = *(const float4*)(wsrc + (size_t)((KT) * 64 + rq * 4 + j) * cI);

#define GU_PACK(BUF, S)                                                       \
  _Pragma("unroll")                                                           \
  for (int i = 0; i < 4; ++i) {                                               \
    uint2v P;                                                                 \
    P.x = pack2(S[0][i], S[1][i]); P.y = pack2(S[2][i], S[3][i]);             \
    *(uint2v*)&sB[BUF][tm][(cg * 4 + i) * 34 + rq * 2] = P;                   \
  }

#define GU_MFMA(CUR, KT)                                                      \
  _Pragma("unroll")                                                           \
  for (int ks = 0; ks < 2; ++ks) {                                            \
    const bf16x8 a = *(const bf16x8*)(ap + (KT) * 64 + ks * 32);              \
    _Pragma("unroll")                                                         \
    for (int ni = 0; ni < 4; ++ni) {                                          \
      const int ba = (q + 16 * ni) * 34 + h16 * 4 + 16 * ks;                  \
      const bf16x8 b = ld_bfrag(&sB[CUR][mat][ba]);                           \
      acc[ni] = __builtin_amdgcn_mfma_f32_16x16x32_bf16(a, b, acc[ni], 0, 0, 0); \
    }                                                                         \
  }

  for (int m0 = c0; m0 < n_e; m0 += 256) {
    if (tid < 64) tokl[tid] = pair_token[off + min(m0 + tid, n_e - 1)];
    __syncthreads();

    const unsigned short* ap =
        xb + (size_t)tokl[msub * 16 + q] * cH + h16 * 8;

    f32x4 acc[4];
#pragma unroll
    for (int ni = 0; ni < 4; ++ni) acc[ni] = (f32x4){0.f, 0.f, 0.f, 0.f};

    GU_LD(s0, 0)
    GU_LD(s1, 1)
    GU_PACK(0, s0)
    __syncthreads();

    for (int kt = 0; kt < 16; kt += 2) {
      if (kt + 2 < 16) { GU_LD(s0, kt + 2) }
      GU_MFMA(0, kt)
      GU_PACK(1, s1)
      __syncthreads();
      if (kt + 3 < 16) { GU_LD(s1, kt + 3) }
      GU_MFMA(1, kt + 1)
      if (kt + 2 < 16) {
        GU_PACK(0, s0)
        __syncthreads();
      }
    }

    // epilogue: exchange up-acc via LDS, gate-waves apply silu(g)*u
    __syncthreads();   // all MFMAs done; sB reusable
    float* uL = (float*)sB;          // [64][68] f32
    if (mat == 1) {
#pragma unroll
      for (int j = 0; j < 4; ++j) {
        const int row = msub * 16 + h16 * 4 + j;
#pragma unroll
        for (int ni = 0; ni < 4; ++ni)
          uL[row * 68 + q + 16 * ni] = acc[ni][j];
      }
    }
    __syncthreads();
    if (mat == 0) {
#pragma unroll
      for (int j = 0; j < 4; ++j) {
        const int row = msub * 16 + h16 * 4 + j;
        const int er = m0 + row;
        if (er < n_e) {
#pragma unroll
          for (int ni = 0; ni < 4; ++ni) {
            const float g = acc[ni][j];
            const float u = uL[row * 68 + q + 16 * ni];
            const float v = (g / (1.f + __expf(-g))) * u;
            act[(size_t)(off + er) * cI + nb + ni * 16 + q] =
                (unsigned short)f2bf(v);
          }
        }
      }
    }
    __syncthreads();   // uL reads done before next m-iter pack
  }
#undef GU_LD
#undef GU_PACK
#undef GU_MFMA
}

// ------------------------------------------------------------------ down ----
// 512 threads = 8 waves: wave wid owns 16 rows -> BM=128, BN=64, BK=64.
// Per-thread: 16 acc + 8 prefetch VGPRs, depth-2 pipeline, no spills.
__global__ __launch_bounds__(512, 4) void down_kernel(
    const unsigned short* __restrict__ act, const float* __restrict__ dw,
    const int* __restrict__ offsets, float* __restrict__ yp) {
  const int e = blockIdx.y;
  const int off = offsets[e];
  const int n_e = offsets[e + 1] - off;
  const int strip = blockIdx.x >> 1;
  const int c0 = (blockIdx.x & 1) * 128;
  if (c0 >= n_e) return;
  const int nb = strip * 64;
  const int tid = threadIdx.x, l = tid & 63, wid = tid >> 6;
  const int q = l & 15, h16 = l >> 4;
  constexpr int NT = cI / 64;                 // 44

  __shared__ unsigned sB[2][2176];

  // staging: 512 threads, 2 rows x float4 each (64 rows x 64 cols f32)
  const int rq = tid >> 4, cg = tid & 15;     // rq 0..31, cg 0..15
  const float* dsrc = dw + (size_t)e * cI * cH + nb + cg * 4;

  float4 s0[2], s1[2];

#define DN_LD(S, KT)                                                          \
  _Pragma("unroll")                                                           \
  for (int i = 0; i < 2; ++i)                                                 \
    S[i] = *(const float4*)(dsrc + (size_t)((KT) * 64 + rq * 2 + i) * cH);

#define DN_PACK(BUF, S)                                                       \
  _Pragma("unroll")                                                           \
  for (int i = 0; i < 4; ++i)                                                 \
    sB[BUF][(cg * 4 + i) * 34 + rq] = pack2(S[0][i], S[1][i]);

#define DN_MFMA(CUR, KT)                                                      \
  _Pragma("unroll")                                                           \
  for (int ks = 0; ks < 2; ++ks) {                                            \
    const bf16x8 a = *(const bf16x8*)(ap + (KT) * 64 + ks * 32);              \
    _Pragma("unroll")                                                         \
    for (int ni = 0; ni < 4; ++ni) {                                          \
      const int ba = (q + 16 * ni) * 34 + h16 * 4 + 16 * ks;                  \
      const bf16x8 b = ld_bfrag(&sB[CUR][ba]);                                \
      acc[ni] = __builtin_amdgcn_mfma_f32_16x16x32_bf16(a, b, acc[ni], 0, 0, 0); \
    }                                                                         \
  }

  for (int m0 = c0; m0 < n_e; m0 += 256) {
    const int row = m0 + wid * 16 + q;
    const unsigned short* ap =
        act + (size_t)(off + min(row, n_e - 1)) * cI + h16 * 8;

    f32x4 acc[4];
#pragma unroll
    for (int ni = 0; ni < 4; ++ni) acc[ni] = (f32x4){0.f, 0.f, 0.f, 0.f};

    DN_LD(s0, 0)
    DN_LD(s1, 1)
    DN_PACK(0, s0)
    __syncthreads();

    for (int kt = 0; kt < NT; kt += 2) {
      if (kt + 2 < NT) { DN_LD(s0, kt + 2) }
      DN_MFMA(0, kt)
      DN_PACK(1, s1)
      __syncthreads();
      if (kt + 3 < NT) { DN_LD(s1, kt + 3) }
      DN_MFMA(1, kt + 1)
      if (kt + 2 < NT) {
        DN_PACK(0, s0)
        __syncthreads();
      }
    }

#pragma unroll
    for (int j = 0; j < 4; ++j) {
      const int er = m0 + wid * 16 + h16 * 4 + j;
      if (er < n_e) {
#pragma unroll
        for (int ni = 0; ni < 4; ++ni)
          yp[(size_t)(off + er) * cH + nb + ni * 16 + q] = acc[ni][j];
      }
    }

    if (m0 + 256 < n_e) __syncthreads();
  }
#undef DN_LD
#undef DN_PACK
#undef DN_MFMA
}

// --------------------------------------------------------------- combine ----
__global__ __launch_bounds__(256) void combine_kernel(
    const float* __restrict__ yp, const int* __restrict__ pair_pos,
    const float* __restrict__ topk_w, float* __restrict__ out) {
  const int t = blockIdx.x;
  const int cb = threadIdx.x * 4;
  float4 s = make_float4(0.f, 0.f, 0.f, 0.f);
#pragma unroll
  for (int j = 0; j < 4; ++j) {
    const int pos = pair_pos[t * 4 + j];
    const float wj = topk_w[t * 4 + j];
    const float4 v = *(const float4*)(yp + (size_t)pos * cH + cb);
    s.x += wj * v.x; s.y += wj * v.y; s.z += wj * v.z; s.w += wj * v.w;
  }
  *(float4*)(out + (size_t)t * cH + cb) = s;
}

// ---------------------------------------------------------------- launch ----
extern "C" void kernel_launch(void* const* d_in, const int* in_sizes, int n_in,
                              void* d_out, int out_size, void* d_ws,
                              size_t ws_size, hipStream_t stream) {
  (void)in_sizes; (void)n_in; (void)out_size; (void)ws_size;
  const float* x = (const float*)d_in[0];
  const float* Wg = (const float*)d_in[1];
  const float* gw = (const float*)d_in[2];
  const float* uw = (const float*)d_in[3];
  const float* dw = (const float*)d_in[4];
  float* out = (float*)d_out;

  char* ws = (char*)d_ws;
  int* counts     = (int*)(ws + 0);          // 16
  int* cursor     = (int*)(ws + 64);         // 16
  int* offsets    = (int*)(ws + 128);        // 17
  int* topk_id    = (int*)(ws + 256);        // 4096
  float* topk_w   = (float*)(ws + 256 + 16384);
  int* pair_token = (int*)(ws + 256 + 32768);
  int* pair_pos   = (int*)(ws + 256 + 49152);
  unsigned short* act = (unsigned short*)(ws + 65792);           // 23.07 MB
  unsigned short* xb  = (unsigned short*)(ws + 65792 + (size_t)4096 * 2816 * 2);
  float* yp = (float*)(ws + 65792 + (size_t)4096 * 2816 * 2 + (size_t)cT * cH * 2);

  (void)hipMemsetAsync(ws, 0, 128, stream);  // counts + cursor

  xcast_kernel<<<cT * cH / (256 * 8), 256, 0, stream>>>(x, xb);
  router_kernel<<<cT, 64, 0, stream>>>(x, Wg, topk_id, topk_w, counts);
  scan_kernel<<<1, 1, 0, stream>>>(counts, offsets);
  scatter_kernel<<<cT * cK / 256, 256, 0, stream>>>(topk_id, offsets, cursor,
                                                    pair_token, pair_pos);
  gateup_kernel<<<dim3(44 * 4, cE), 512, 0, stream>>>(xb, gw, uw, offsets,
                                                      pair_token, act);
  down_kernel<<<dim3(16 * 2, cE), 512, 0, stream>>>(act, dw, offsets, yp);
  combine_kernel<<<cT, 256, 0, stream>>>(yp, pair_pos, topk_w, out);
}

// Round 8
// 516.234 us; speedup vs baseline: 1.0480x; 1.0480x over previous
//
#include <hip/hip_runtime.h>

static constexpr int cT = 1024;   // tokens
static constexpr int cH = 1024;   // hidden
static constexpr int cI = 2816;   // intermediate
static constexpr int cE = 16;     // experts
static constexpr int cK = 4;      // top-k

typedef __attribute__((ext_vector_type(8))) short bf16x8;
typedef __attribute__((ext_vector_type(4))) float f32x4;
typedef __attribute__((ext_vector_type(2))) unsigned uint2v;
typedef __attribute__((ext_vector_type(4))) unsigned uint4v;

__device__ __forceinline__ unsigned f2bf(float f) {
  unsigned u = __float_as_uint(f);
  return (u + 0x7FFFu + ((u >> 16) & 1u)) >> 16;   // RNE f32->bf16
}
__device__ __forceinline__ unsigned pack2(float lo, float hi) {
  return f2bf(lo) | (f2bf(hi) << 16);
}

// Two ds_read_b64 (stride-34-uint layout is 8B- but not 16B-aligned).
__device__ __forceinline__ bf16x8 ld_bfrag(const unsigned* p) {
  union { uint2v d[2]; bf16x8 v; } r;
  r.d[0] = *(const uint2v*)p;
  r.d[1] = *(const uint2v*)(p + 2);
  return r.v;
}

// ------------------------------------------------------------- x -> bf16 ----
__global__ __launch_bounds__(256) void xcast_kernel(
    const float* __restrict__ x, unsigned short* __restrict__ xb) {
  const int i = blockIdx.x * 256 + threadIdx.x;
  const float4* xv = (const float4*)x;
  const float4 a = xv[i * 2], b = xv[i * 2 + 1];
  uint4v o;
  o.x = pack2(a.x, a.y); o.y = pack2(a.z, a.w);
  o.z = pack2(b.x, b.y); o.w = pack2(b.z, b.w);
  ((uint4v*)xb)[i] = o;
}

// ---------------------------------------------------------------- router ----
__global__ __launch_bounds__(64) void router_kernel(
    const float* __restrict__ x, const float* __restrict__ Wg,
    int* __restrict__ topk_id, float* __restrict__ topk_w,
    int* __restrict__ counts) {
  const int t = blockIdx.x;
  const int l = threadIdx.x;

  float xa[16];
#pragma unroll
  for (int i = 0; i < 16; ++i) xa[i] = x[(size_t)t * cH + l + 64 * i];

  float lg[16];
#pragma unroll
  for (int e = 0; e < 16; ++e) {
    float s = 0.f;
#pragma unroll
    for (int i = 0; i < 16; ++i) s += xa[i] * Wg[(size_t)e * cH + l + 64 * i];
#pragma unroll
    for (int d = 1; d < 64; d <<= 1) s += __shfl_xor(s, d);
    lg[e] = s;
  }

  if (l == 0) {
    int ids[4]; float vals[4];
    unsigned taken = 0;
#pragma unroll
    for (int j = 0; j < 4; ++j) {
      float m = -1e30f; int mi = 0;
#pragma unroll
      for (int e = 0; e < 16; ++e) {
        bool better = !((taken >> e) & 1u) && lg[e] > m;
        if (better) { m = lg[e]; mi = e; }
      }
      taken |= 1u << mi; ids[j] = mi; vals[j] = m;
    }
    const float mx = vals[0];
    float s = 0.f;
#pragma unroll
    for (int j = 0; j < 4; ++j) { vals[j] = __expf(vals[j] - mx); s += vals[j]; }
    const float inv = 1.f / s;
#pragma unroll
    for (int j = 0; j < 4; ++j) {
      topk_id[t * 4 + j] = ids[j];
      topk_w[t * 4 + j] = vals[j] * inv;
      atomicAdd(&counts[ids[j]], 1);
    }
  }
}

__global__ void scan_kernel(const int* __restrict__ counts,
                            int* __restrict__ offsets) {
  if (threadIdx.x == 0 && blockIdx.x == 0) {
    int acc = 0;
    for (int e = 0; e < cE; ++e) { offsets[e] = acc; acc += counts[e]; }
    offsets[cE] = acc;
  }
}

__global__ __launch_bounds__(256) void scatter_kernel(
    const int* __restrict__ topk_id, const int* __restrict__ offsets,
    int* __restrict__ cursor, int* __restrict__ pair_token,
    int* __restrict__ pair_pos) {
  const int i = blockIdx.x * 256 + threadIdx.x;   // 0..4095
  const int t = i >> 2;
  const int e = topk_id[i];
  const int pos = offsets[e] + atomicAdd(&cursor[e], 1);
  pair_token[pos] = t;
  pair_pos[i] = pos;
}

// ---------------------------------------------------------------- gate+up ---
// Block = (32-col strip, expert): this block is the ONLY reader of its weight
// strip -> weights stream from HBM exactly once (no cache-sharing needed).
// 8 waves = 2 mats x 4 msubs; msub owns 96 rows (chunk 384 >= typical n_e).
// Single-set register prefetch: PACK(kt+1) -> LD(kt+2) -> MFMA(kt) -> barrier.
__global__ __launch_bounds__(512, 4) void gateup_kernel(
    const unsigned short* __restrict__ xb, const float* __restrict__ gw,
    const float* __restrict__ uw, const int* __restrict__ offsets,
    const int* __restrict__ pair_token, unsigned short* __restrict__ act) {
  const int e = blockIdx.y;
  const int off = offsets[e];
  const int n_e = offsets[e + 1] - off;
  if (n_e <= 0) return;
  const int nb = blockIdx.x * 32;
  const int tid = threadIdx.x, l = tid & 63, wid = tid >> 6;
  const int q = l & 15, h16 = l >> 4;
  const int mat = wid & 1, msub = wid >> 1;

  __shared__ unsigned smem[13056];   // sB: 2buf x 2mat x 1088 | uL: 384x34 f32
  __shared__ int tokl[384];

  // staging: tm = matrix; 256 thr/mat; rq = row-pair 0..31, cg = col-quad 0..7
  const int tm = tid >> 8, tt = tid & 255;
  const int rq = tt >> 3, cg = tt & 7;
  const float* wsrc = (tm ? uw : gw) + (size_t)e * cH * cI + nb + cg * 4;

  float4 s0[2];

#define GU_LD(KT)                                                             \
  _Pragma("unroll")                                                           \
  for (int i = 0; i < 2; ++i)                                                 \
    s0[i] = *(const float4*)(wsrc + (size_t)((KT) * 64 + rq * 2 + i) * cI);

#define GU_PACK(BUF)                                                          \
  _Pragma("unroll")                                                           \
  for (int i = 0; i < 4; ++i)                                                 \
    smem[((BUF) * 2 + tm) * 1088 + (cg * 4 + i) * 34 + rq] =                  \
        pack2(s0[0][i], s0[1][i]);

#define GU_MFMA(CUR, KT)                                                      \
  _Pragma("unroll")                                                           \
  for (int ks = 0; ks < 2; ++ks) {                                            \
    bf16x8 af[6];                                                             \
    _Pragma("unroll")                                                         \
    for (int mf = 0; mf < 6; ++mf)                                            \
      af[mf] = *(const bf16x8*)(ap[mf] + (KT) * 64 + ks * 32);                \
    _Pragma("unroll")                                                         \
    for (int ni = 0; ni < 2; ++ni) {                                          \
      const unsigned* bp = &smem[((CUR) * 2 + mat) * 1088 +                   \
                                 (q + 16 * ni) * 34 + h16 * 4 + 16 * ks];     \
      const bf16x8 b = ld_bfrag(bp);                                          \
      _Pragma("unroll")                                                       \
      for (int mf = 0; mf < 6; ++mf)                                          \
        acc[mf][ni] =                                                         \
            __builtin_amdgcn_mfma_f32_16x16x32_bf16(af[mf], b, acc[mf][ni], 0, 0, 0); \
    }                                                                         \
  }

  for (int m0 = 0; m0 < n_e; m0 += 384) {
    if (tid < 384) tokl[tid] = pair_token[off + min(m0 + tid, n_e - 1)];
    // (visible after the prologue barrier below)

    const unsigned short* ap[6];
#pragma unroll
    for (int mf = 0; mf < 6; ++mf) {
      const int r = min(msub * 96 + mf * 16 + q, 383);
      ap[mf] = xb + 0;   // patched after tokl barrier; use row idx for now
    }

    f32x4 acc[6][2];
#pragma unroll
    for (int mf = 0; mf < 6; ++mf)
#pragma unroll
      for (int ni = 0; ni < 2; ++ni) acc[mf][ni] = (f32x4){0.f, 0.f, 0.f, 0.f};

    GU_LD(0)
    GU_PACK(0)
    GU_LD(1)
    __syncthreads();   // tile0 packed; tokl visible

#pragma unroll
    for (int mf = 0; mf < 6; ++mf) {
      const int r = msub * 96 + mf * 16 + q;
      ap[mf] = xb + (size_t)tokl[min(r, n_e - 1 - m0 < 383 ? (r < n_e - m0 ? r : n_e - 1 - m0) : r)] * cH + h16 * 8;
    }

    for (int kt = 0; kt < 16; ++kt) {
      const int cur = kt & 1;
      if (kt + 1 < 16) { GU_PACK(1 - cur) }
      if (kt + 2 < 16) { GU_LD(kt + 2) }
      GU_MFMA(cur, kt)
      if (kt + 1 < 16) __syncthreads();
    }

    // epilogue: up-waves publish acc, gate-waves apply silu(g)*u
    __syncthreads();
    float* uL = (float*)smem;   // [384][34]
    if (mat == 1) {
#pragma unroll
      for (int mf = 0; mf < 6; ++mf)
#pragma unroll
        for (int j = 0; j < 4; ++j) {
          const int row = msub * 96 + mf * 16 + h16 * 4 + j;
#pragma unroll
          for (int ni = 0; ni < 2; ++ni)
            uL[row * 34 + q + 16 * ni] = acc[mf][ni][j];
        }
    }
    __syncthreads();
    if (mat == 0) {
#pragma unroll
      for (int mf = 0; mf < 6; ++mf)
#pragma unroll
        for (int j = 0; j < 4; ++j) {
          const int row = msub * 96 + mf * 16 + h16 * 4 + j;
          const int er = m0 + row;
          if (er < n_e) {
#pragma unroll
            for (int ni = 0; ni < 2; ++ni) {
              const float g = acc[mf][ni][j];
              const float u = uL[row * 34 + q + 16 * ni];
              const float v = (g / (1.f + __expf(-g))) * u;
              act[(size_t)(off + er) * cI + nb + ni * 16 + q] =
                  (unsigned short)f2bf(v);
            }
          }
        }
    }
    __syncthreads();
  }
#undef GU_LD
#undef GU_PACK
#undef GU_MFMA
}

// ------------------------------------------------------------------ down ----
// Block = (64-col strip, expert), grid 16x16. 8 waves x 48 rows = chunk 384;
// dw streamed from HBM exactly once; act is L3-resident.
__global__ __launch_bounds__(512, 4) void down_kernel(
    const unsigned short* __restrict__ act, const float* __restrict__ dw,
    const int* __restrict__ offsets, float* __restrict__ yp) {
  const int e = blockIdx.y;
  const int off = offsets[e];
  const int n_e = offsets[e + 1] - off;
  if (n_e <= 0) return;
  const int nb = blockIdx.x * 64;
  const int tid = threadIdx.x, l = tid & 63, wid = tid >> 6;
  const int q = l & 15, h16 = l >> 4;
  constexpr int NT = cI / 64;                 // 44

  __shared__ unsigned sB[2][2176];            // [buf][col*34 + kpair]

  // staging: rq = row-pair 0..31, cg = col-quad 0..15
  const int rq = tid >> 4, cg = tid & 15;
  const float* dsrc = dw + (size_t)e * cI * cH + nb + cg * 4;

  float4 s0[2];

#define DN_LD(KT)                                                             \
  _Pragma("unroll")                                                           \
  for (int i = 0; i < 2; ++i)                                                 \
    s0[i] = *(const float4*)(dsrc + (size_t)((KT) * 64 + rq * 2 + i) * cH);

#define DN_PACK(BUF)                                                          \
  _Pragma("unroll")                                                           \
  for (int i = 0; i < 4; ++i)                                                 \
    sB[BUF][(cg * 4 + i) * 34 + rq] = pack2(s0[0][i], s0[1][i]);

#define DN_MFMA(CUR, KT)                                                      \
  _Pragma("unroll")                                                           \
  for (int ks = 0; ks < 2; ++ks) {                                            \
    bf16x8 af[3];                                                             \
    _Pragma("unroll")                                                         \
    for (int mf = 0; mf < 3; ++mf)                                            \
      af[mf] = *(const bf16x8*)(ap[mf] + (KT) * 64 + ks * 32);                \
    _Pragma("unroll")                                                         \
    for (int ni = 0; ni < 4; ++ni) {                                          \
      const bf16x8 b = ld_bfrag(&sB[CUR][(q + 16 * ni) * 34 + h16 * 4 + 16 * ks]); \
      _Pragma("unroll")                                                       \
      for (int mf = 0; mf < 3; ++mf)                                          \
        acc[mf][ni] =                                                         \
            __builtin_amdgcn_mfma_f32_16x16x32_bf16(af[mf], b, acc[mf][ni], 0, 0, 0); \
    }                                                                         \
  }

  for (int m0 = 0; m0 < n_e; m0 += 384) {
    const unsigned short* ap[3];
#pragma unroll
    for (int mf = 0; mf < 3; ++mf) {
      const int r = min(m0 + wid * 48 + mf * 16 + q, n_e - 1);
      ap[mf] = act + (size_t)(off + r) * cI + h16 * 8;
    }

    f32x4 acc[3][4];
#pragma unroll
    for (int mf = 0; mf < 3; ++mf)
#pragma unroll
      for (int ni = 0; ni < 4; ++ni) acc[mf][ni] = (f32x4){0.f, 0.f, 0.f, 0.f};

    DN_LD(0)
    DN_PACK(0)
    DN_LD(1)
    __syncthreads();

    for (int kt = 0; kt < NT; ++kt) {
      const int cur = kt & 1;
      if (kt + 1 < NT) { DN_PACK(1 - cur) }
      if (kt + 2 < NT) { DN_LD(kt + 2) }
      DN_MFMA(cur, kt)
      if (kt + 1 < NT) __syncthreads();
    }

#pragma unroll
    for (int mf = 0; mf < 3; ++mf)
#pragma unroll
      for (int j = 0; j < 4; ++j) {
        const int er = m0 + wid * 48 + mf * 16 + h16 * 4 + j;
        if (er < n_e) {
#pragma unroll
          for (int ni = 0; ni < 4; ++ni)
            yp[(size_t)(off + er) * cH + nb + ni * 16 + q] = acc[mf][ni][j];
        }
      }

    if (m0 + 384 < n_e) __syncthreads();
  }
#undef DN_LD
#undef DN_PACK
#undef DN_MFMA
}

// --------------------------------------------------------------- combine ----
__global__ __launch_bounds__(256) void combine_kernel(
    const float* __restrict__ yp, const int* __restrict__ pair_pos,
    const float* __restrict__ topk_w, float* __restrict__ out) {
  const int t = blockIdx.x;
  const int cb = threadIdx.x * 4;
  float4 s = make_float4(0.f, 0.f, 0.f, 0.f);
#pragma unroll
  for (int j = 0; j < 4; ++j) {
    const int pos = pair_pos[t * 4 + j];
    const float wj = topk_w[t * 4 + j];
    const float4 v = *(const float4*)(yp + (size_t)pos * cH + cb);
    s.x += wj * v.x; s.y += wj * v.y; s.z += wj * v.z; s.w += wj * v.w;
  }
  *(float4*)(out + (size_t)t * cH + cb) = s;
}

// ---------------------------------------------------------------- launch ----
extern "C" void kernel_launch(void* const* d_in, const int* in_sizes, int n_in,
                              void* d_out, int out_size, void* d_ws,
                              size_t ws_size, hipStream_t stream) {
  (void)in_sizes; (void)n_in; (void)out_size; (void)ws_size;
  const float* x = (const float*)d_in[0];
  const float* Wg = (const float*)d_in[1];
  const float* gw = (const float*)d_in[2];
  const float* uw = (const float*)d_in[3];
  const float* dw = (const float*)d_in[4];
  float* out = (float*)d_out;

  char* ws = (char*)d_ws;
  int* counts     = (int*)(ws + 0);          // 16
  int* cursor     = (int*)(ws + 64);         // 16
  int* offsets    = (int*)(ws + 128);        // 17
  int* topk_id    = (int*)(ws + 256);        // 4096
  float* topk_w   = (float*)(ws + 256 + 16384);
  int* pair_token = (int*)(ws + 256 + 32768);
  int* pair_pos   = (int*)(ws + 256 + 49152);
  unsigned short* act = (unsigned short*)(ws + 65792);           // 23.07 MB
  unsigned short* xb  = (unsigned short*)(ws + 65792 + (size_t)4096 * 2816 * 2);
  float* yp = (float*)(ws + 65792 + (size_t)4096 * 2816 * 2 + (size_t)cT * cH * 2);

  (void)hipMemsetAsync(ws, 0, 128, stream);  // counts + cursor

  xcast_kernel<<<cT * cH / (256 * 8), 256, 0, stream>>>(x, xb);
  router_kernel<<<cT, 64, 0, stream>>>(x, Wg, topk_id, topk_w, counts);
  scan_kernel<<<1, 1, 0, stream>>>(counts, offsets);
  scatter_kernel<<<cT * cK / 256, 256, 0, stream>>>(topk_id, offsets, cursor,
                                                    pair_token, pair_pos);
  gateup_kernel<<<dim3(cI / 32, cE), 512, 0, stream>>>(xb, gw, uw, offsets,
                                                       pair_token, act);
  down_kernel<<<dim3(cH / 64, cE), 512, 0, stream>>>(act, dw, offsets, yp);
  combine_kernel<<<cT, 256, 0, stream>>>(yp, pair_pos, topk_w, out);
}

// Round 9
// 445.000 us; speedup vs baseline: 1.2157x; 1.1601x over previous
//
#include <hip/hip_runtime.h>

static constexpr int cT = 1024;   // tokens
static constexpr int cH = 1024;   // hidden
static constexpr int cI = 2816;   // intermediate
static constexpr int cE = 16;     // experts
static constexpr int cK = 4;      // top-k

typedef __attribute__((ext_vector_type(8))) short bf16x8;
typedef __attribute__((ext_vector_type(4))) float f32x4;
typedef __attribute__((ext_vector_type(2))) unsigned uint2v;
typedef __attribute__((ext_vector_type(4))) unsigned uint4v;

__device__ __forceinline__ unsigned f2bf(float f) {
  unsigned u = __float_as_uint(f);
  return (u + 0x7FFFu + ((u >> 16) & 1u)) >> 16;   // RNE f32->bf16
}
__device__ __forceinline__ unsigned pack2(float lo, float hi) {
  return f2bf(lo) | (f2bf(hi) << 16);
}

// Two ds_read_b64 (stride-34-uint layout is 8B- but not 16B-aligned).
__device__ __forceinline__ bf16x8 ld_bfrag(const unsigned* p) {
  union { uint2v d[2]; bf16x8 v; } r;
  r.d[0] = *(const uint2v*)p;
  r.d[1] = *(const uint2v*)(p + 2);
  return r.v;
}

// ------------------------------------------------------------- x -> bf16 ----
__global__ __launch_bounds__(256) void xcast_kernel(
    const float* __restrict__ x, unsigned short* __restrict__ xb) {
  const int i = blockIdx.x * 256 + threadIdx.x;
  const float4* xv = (const float4*)x;
  const float4 a = xv[i * 2], b = xv[i * 2 + 1];
  uint4v o;
  o.x = pack2(a.x, a.y); o.y = pack2(a.z, a.w);
  o.z = pack2(b.x, b.y); o.w = pack2(b.z, b.w);
  ((uint4v*)xb)[i] = o;
}

// ---------------------------------------------------------------- router ----
__global__ __launch_bounds__(64) void router_kernel(
    const float* __restrict__ x, const float* __restrict__ Wg,
    int* __restrict__ topk_id, float* __restrict__ topk_w,
    int* __restrict__ counts) {
  const int t = blockIdx.x;
  const int l = threadIdx.x;

  float xa[16];
#pragma unroll
  for (int i = 0; i < 16; ++i) xa[i] = x[(size_t)t * cH + l + 64 * i];

  float lg[16];
#pragma unroll
  for (int e = 0; e < 16; ++e) {
    float s = 0.f;
#pragma unroll
    for (int i = 0; i < 16; ++i) s += xa[i] * Wg[(size_t)e * cH + l + 64 * i];
#pragma unroll
    for (int d = 1; d < 64; d <<= 1) s += __shfl_xor(s, d);
    lg[e] = s;
  }

  if (l == 0) {
    int ids[4]; float vals[4];
    unsigned taken = 0;
#pragma unroll
    for (int j = 0; j < 4; ++j) {
      float m = -1e30f; int mi = 0;
#pragma unroll
      for (int e = 0; e < 16; ++e) {
        bool better = !((taken >> e) & 1u) && lg[e] > m;
        if (better) { m = lg[e]; mi = e; }
      }
      taken |= 1u << mi; ids[j] = mi; vals[j] = m;
    }
    const float mx = vals[0];
    float s = 0.f;
#pragma unroll
    for (int j = 0; j < 4; ++j) { vals[j] = __expf(vals[j] - mx); s += vals[j]; }
    const float inv = 1.f / s;
#pragma unroll
    for (int j = 0; j < 4; ++j) {
      topk_id[t * 4 + j] = ids[j];
      topk_w[t * 4 + j] = vals[j] * inv;
      atomicAdd(&counts[ids[j]], 1);
    }
  }
}

__global__ void scan_kernel(const int* __restrict__ counts,
                            int* __restrict__ offsets) {
  if (threadIdx.x == 0 && blockIdx.x == 0) {
    int acc = 0;
    for (int e = 0; e < cE; ++e) { offsets[e] = acc; acc += counts[e]; }
    offsets[cE] = acc;
  }
}

__global__ __launch_bounds__(256) void scatter_kernel(
    const int* __restrict__ topk_id, const int* __restrict__ offsets,
    int* __restrict__ cursor, int* __restrict__ pair_token,
    int* __restrict__ pair_pos) {
  const int i = blockIdx.x * 256 + threadIdx.x;   // 0..4095
  const int t = i >> 2;
  const int e = topk_id[i];
  const int pos = offsets[e] + atomicAdd(&cursor[e], 1);
  pair_token[pos] = t;
  pair_pos[i] = pos;
}

// ---------------------------------------------------------------- gate+up ---
// Block = (32-col strip, expert): sole reader of its weight strip -> weights
// fetched from HBM exactly once. 8 waves x 48 rows = chunk 384 (covers any
// realistic n_e in ONE pass). Each wave computes BOTH gate and up for its
// rows (silu wave-local: no LDS exchange; A-gathers shared by both mats).
// LDS: just B dbuf (19 KB) -> 3-4 blocks/CU for cross-block latency hiding.
__global__ __launch_bounds__(512, 4) void gateup_kernel(
    const unsigned short* __restrict__ xb, const float* __restrict__ gw,
    const float* __restrict__ uw, const int* __restrict__ offsets,
    const int* __restrict__ pair_token, unsigned short* __restrict__ act) {
  const int e = blockIdx.y;
  const int off = offsets[e];
  const int n_e = offsets[e + 1] - off;
  if (n_e <= 0) return;
  const int nb = blockIdx.x * 32;
  const int tid = threadIdx.x, l = tid & 63, wid = tid >> 6;
  const int q = l & 15, h16 = l >> 4;

  __shared__ unsigned sB[2][2][1088];   // [buf][mat][col*34 + kpair]
  __shared__ int tokl[384];

  // staging: tm = matrix (256 thr each); rq = row-pair 0..31, cg = col-quad 0..7
  const int tm = tid >> 8, tt = tid & 255;
  const int rq = tt >> 3, cg = tt & 7;
  const float* wsrc = (tm ? uw : gw) + (size_t)e * cH * cI + nb + cg * 4;

  float4 s0[2];

#define GU_LD(KT)                                                             \
  _Pragma("unroll")                                                           \
  for (int i = 0; i < 2; ++i)                                                 \
    s0[i] = *(const float4*)(wsrc + (size_t)((KT) * 64 + rq * 2 + i) * cI);

#define GU_PACK(BUF)                                                          \
  _Pragma("unroll")                                                           \
  for (int i = 0; i < 4; ++i)                                                 \
    sB[BUF][tm][(cg * 4 + i) * 34 + rq] = pack2(s0[0][i], s0[1][i]);

#define GU_MFMA(CUR, KT)                                                      \
  _Pragma("unroll")                                                           \
  for (int ks = 0; ks < 2; ++ks) {                                            \
    bf16x8 af[3];                                                             \
    _Pragma("unroll")                                                         \
    for (int mf = 0; mf < 3; ++mf)                                            \
      af[mf] = *(const bf16x8*)(ap[mf] + (KT) * 64 + ks * 32);                \
    _Pragma("unroll")                                                         \
    for (int mt = 0; mt < 2; ++mt) {                                          \
      _Pragma("unroll")                                                       \
      for (int ni = 0; ni < 2; ++ni) {                                        \
        const bf16x8 b =                                                      \
            ld_bfrag(&sB[CUR][mt][(q + 16 * ni) * 34 + h16 * 4 + 16 * ks]);   \
        _Pragma("unroll")                                                     \
        for (int mf = 0; mf < 3; ++mf)                                        \
          acc[mt][mf][ni] = __builtin_amdgcn_mfma_f32_16x16x32_bf16(          \
              af[mf], b, acc[mt][mf][ni], 0, 0, 0);                           \
      }                                                                       \
    }                                                                         \
  }

  for (int m0 = 0; m0 < n_e; m0 += 384) {
    if (tid < 384) tokl[tid] = pair_token[off + min(m0 + tid, n_e - 1)];

    f32x4 acc[2][3][2];
#pragma unroll
    for (int mt = 0; mt < 2; ++mt)
#pragma unroll
      for (int mf = 0; mf < 3; ++mf)
#pragma unroll
        for (int ni = 0; ni < 2; ++ni)
          acc[mt][mf][ni] = (f32x4){0.f, 0.f, 0.f, 0.f};

    GU_LD(0)
    GU_PACK(0)
    GU_LD(1)
    __syncthreads();   // tile0 packed; tokl visible

    const unsigned short* ap[3];
#pragma unroll
    for (int mf = 0; mf < 3; ++mf)
      ap[mf] = xb + (size_t)tokl[wid * 48 + mf * 16 + q] * cH + h16 * 8;

    for (int kt = 0; kt < 16; ++kt) {
      const int cur = kt & 1;
      if (kt + 1 < 16) { GU_PACK(1 - cur) }
      if (kt + 2 < 16) { GU_LD(kt + 2) }
      GU_MFMA(cur, kt)
      if (kt + 1 < 16) __syncthreads();
    }

    // epilogue: silu(g)*u -> bf16 act (both mats are wave-local)
#pragma unroll
    for (int mf = 0; mf < 3; ++mf)
#pragma unroll
      for (int j = 0; j < 4; ++j) {
        const int er = m0 + wid * 48 + mf * 16 + h16 * 4 + j;
        if (er < n_e) {
#pragma unroll
          for (int ni = 0; ni < 2; ++ni) {
            const float g = acc[0][mf][ni][j];
            const float u = acc[1][mf][ni][j];
            const float v = (g / (1.f + __expf(-g))) * u;
            act[(size_t)(off + er) * cI + nb + ni * 16 + q] =
                (unsigned short)f2bf(v);
          }
        }
      }
  }
#undef GU_LD
#undef GU_PACK
#undef GU_MFMA
}

// ------------------------------------------------------------------ down ----
// Block = (32-col strip, expert), grid 32x16 = 512 blocks (2+ blocks/CU).
// 8 waves x 48 rows = chunk 384; dw fetched from HBM exactly once; act L3.
__global__ __launch_bounds__(512, 4) void down_kernel(
    const unsigned short* __restrict__ act, const float* __restrict__ dw,
    const int* __restrict__ offsets, float* __restrict__ yp) {
  const int e = blockIdx.y;
  const int off = offsets[e];
  const int n_e = offsets[e + 1] - off;
  if (n_e <= 0) return;
  const int nb = blockIdx.x * 32;
  const int tid = threadIdx.x, l = tid & 63, wid = tid >> 6;
  const int q = l & 15, h16 = l >> 4;
  constexpr int NT = cI / 64;                 // 44

  __shared__ unsigned sB[2][1088];            // [buf][col*34 + kpair]

  // staging: rq = row-pair 0..31, cg = col-pair 0..15 (float2 x 2 rows)
  const int rq = tid >> 4, cg = tid & 15;
  const float* dsrc = dw + (size_t)e * cI * cH + nb + cg * 2;

  float2 s0[2];

#define DN_LD(KT)                                                             \
  _Pragma("unroll")                                                           \
  for (int i = 0; i < 2; ++i)                                                 \
    s0[i] = *(const float2*)(dsrc + (size_t)((KT) * 64 + rq * 2 + i) * cH);

#define DN_PACK(BUF)                                                          \
  sB[BUF][(cg * 2) * 34 + rq] = pack2(s0[0].x, s0[1].x);                      \
  sB[BUF][(cg * 2 + 1) * 34 + rq] = pack2(s0[0].y, s0[1].y);

#define DN_MFMA(CUR, KT)                                                      \
  _Pragma("unroll")                                                           \
  for (int ks = 0; ks < 2; ++ks) {                                            \
    bf16x8 af[3];                                                             \
    _Pragma("unroll")                                                         \
    for (int mf = 0; mf < 3; ++mf)                                            \
      af[mf] = *(const bf16x8*)(ap[mf] + (KT) * 64 + ks * 32);                \
    _Pragma("unroll")                                                         \
    for (int ni = 0; ni < 2; ++ni) {                                          \
      const bf16x8 b =                                                        \
          ld_bfrag(&sB[CUR][(q + 16 * ni) * 34 + h16 * 4 + 16 * ks]);         \
      _Pragma("unroll")                                                       \
      for (int mf = 0; mf < 3; ++mf)                                          \
        acc[mf][ni] = __builtin_amdgcn_mfma_f32_16x16x32_bf16(                \
            af[mf], b, acc[mf][ni], 0, 0, 0);                                 \
    }                                                                         \
  }

  for (int m0 = 0; m0 < n_e; m0 += 384) {
    const unsigned short* ap[3];
#pragma unroll
    for (int mf = 0; mf < 3; ++mf) {
      const int r = min(m0 + wid * 48 + mf * 16 + q, n_e - 1);
      ap[mf] = act + (size_t)(off + r) * cI + h16 * 8;
    }

    f32x4 acc[3][2];
#pragma unroll
    for (int mf = 0; mf < 3; ++mf)
#pragma unroll
      for (int ni = 0; ni < 2; ++ni) acc[mf][ni] = (f32x4){0.f, 0.f, 0.f, 0.f};

    DN_LD(0)
    DN_PACK(0)
    DN_LD(1)
    __syncthreads();

    for (int kt = 0; kt < NT; ++kt) {
      const int cur = kt & 1;
      if (kt + 1 < NT) { DN_PACK(1 - cur) }
      if (kt + 2 < NT) { DN_LD(kt + 2) }
      DN_MFMA(cur, kt)
      if (kt + 1 < NT) __syncthreads();
    }

#pragma unroll
    for (int mf = 0; mf < 3; ++mf)
#pragma unroll
      for (int j = 0; j < 4; ++j) {
        const int er = m0 + wid * 48 + mf * 16 + h16 * 4 + j;
        if (er < n_e) {
#pragma unroll
          for (int ni = 0; ni < 2; ++ni)
            yp[(size_t)(off + er) * cH + nb + ni * 16 + q] = acc[mf][ni][j];
        }
      }

    if (m0 + 384 < n_e) __syncthreads();
  }
#undef DN_LD
#undef DN_PACK
#undef DN_MFMA
}

// --------------------------------------------------------------- combine ----
__global__ __launch_bounds__(256) void combine_kernel(
    const float* __restrict__ yp, const int* __restrict__ pair_pos,
    const float* __restrict__ topk_w, float* __restrict__ out) {
  const int t = blockIdx.x;
  const int cb = threadIdx.x * 4;
  float4 s = make_float4(0.f, 0.f, 0.f, 0.f);
#pragma unroll
  for (int j = 0; j < 4; ++j) {
    const int pos = pair_pos[t * 4 + j];
    const float wj = topk_w[t * 4 + j];
    const float4 v = *(const float4*)(yp + (size_t)pos * cH + cb);
    s.x += wj * v.x; s.y += wj * v.y; s.z += wj * v.z; s.w += wj * v.w;
  }
  *(float4*)(out + (size_t)t * cH + cb) = s;
}

// ---------------------------------------------------------------- launch ----
extern "C" void kernel_launch(void* const* d_in, const int* in_sizes, int n_in,
                              void* d_out, int out_size, void* d_ws,
                              size_t ws_size, hipStream_t stream) {
  (void)in_sizes; (void)n_in; (void)out_size; (void)ws_size;
  const float* x = (const float*)d_in[0];
  const float* Wg = (const float*)d_in[1];
  const float* gw = (const float*)d_in[2];
  const float* uw = (const float*)d_in[3];
  const float* dw = (const float*)d_in[4];
  float* out = (float*)d_out;

  char* ws = (char*)d_ws;
  int* counts     = (int*)(ws + 0);          // 16
  int* cursor     = (int*)(ws + 64);         // 16
  int* offsets    = (int*)(ws + 128);        // 17
  int* topk_id    = (int*)(ws + 256);        // 4096
  float* topk_w   = (float*)(ws + 256 + 16384);
  int* pair_token = (int*)(ws + 256 + 32768);
  int* pair_pos   = (int*)(ws + 256 + 49152);
  unsigned short* act = (unsigned short*)(ws + 65792);           // 23.07 MB
  unsigned short* xb  = (unsigned short*)(ws + 65792 + (size_t)4096 * 2816 * 2);
  float* yp = (float*)(ws + 65792 + (size_t)4096 * 2816 * 2 + (size_t)cT * cH * 2);

  (void)hipMemsetAsync(ws, 0, 128, stream);  // counts + cursor

  xcast_kernel<<<cT * cH / (256 * 8), 256, 0, stream>>>(x, xb);
  router_kernel<<<cT, 64, 0, stream>>>(x, Wg, topk_id, topk_w, counts);
  scan_kernel<<<1, 1, 0, stream>>>(counts, offsets);
  scatter_kernel<<<cT * cK / 256, 256, 0, stream>>>(topk_id, offsets, cursor,
                                                    pair_token, pair_pos);
  gateup_kernel<<<dim3(cI / 32, cE), 512, 0, stream>>>(xb, gw, uw, offsets,
                                                       pair_token, act);
  down_kernel<<<dim3(cH / 32, cE), 512, 0, stream>>>(act, dw, offsets, yp);
  combine_kernel<<<cT, 256, 0, stream>>>(yp, pair_pos, topk_w, out);
}